// Round 10
// baseline (297.595 us; speedup 1.0000x reference)
//
#include <hip/hip_runtime.h>

#define L_SEQ 2048
#define DMODEL 1024
#define DINNER 2048
#define NCHUNK 64
#define TCHUNK 32

typedef __attribute__((ext_vector_type(8))) short bf16x8;
typedef __attribute__((ext_vector_type(4))) float f32x4;

__device__ __forceinline__ float bf2f(unsigned short u) {
  return __uint_as_float(((unsigned)u) << 16);
}
__device__ __forceinline__ unsigned short f2bf(float f) {
  unsigned u = __float_as_uint(f);
  return (unsigned short)((u + 0x7FFFu + ((u >> 16) & 1u)) >> 16);
}
__device__ __forceinline__ void gload_lds16(const void* g, void* l) {
  __builtin_amdgcn_global_load_lds(
      (const __attribute__((address_space(1))) void*)g,
      (__attribute__((address_space(3))) void*)l, 16, 0, 0);
}

// ---------------- fused fp32 -> bf16 converts ----------------
__global__ __launch_bounds__(256) void cvt_all(
    const float4* __restrict__ x, const float4* __restrict__ Win,
    const float4* __restrict__ Wdt, const float4* __restrict__ Wx,
    const float4* __restrict__ Wout,
    ushort4* __restrict__ xbf, ushort4* __restrict__ winb, ushort4* __restrict__ wcomb,
    ushort4* __restrict__ wcombx, ushort4* __restrict__ woutb, ushort4* __restrict__ wcombz) {
  int i = blockIdx.x * 256 + threadIdx.x;
  const float4* s; ushort4* d; int j;
  if (i < 524288)        { s = x;    d = xbf;    j = i; }
  else if (i < 1572864)  { s = Win;  d = winb;   j = i - 524288; }
  else if (i < 2621440)  { s = Wdt;  d = wcomb;  j = i - 1572864; }
  else if (i < 2637824)  { s = Wx;   d = wcombx; j = i - 2621440; }
  else if (i < 3162112)  { s = Wout; d = woutb;  j = i - 2637824; }
  else                   { wcombz[i - 3162112] = ushort4{0, 0, 0, 0}; return; }
  float4 v = s[j];
  ushort4 o;
  o.x = f2bf(v.x); o.y = f2bf(v.y); o.z = f2bf(v.z); o.w = f2bf(v.w);
  d[j] = o;
}

// ---------------- bf16 GEMM, C = A[M,K] * B[N,K]^T ----------------
// Tile BM=MI*32 x BN=NJ*32, BK=32, 4 waves as 2x2 (wave sub-tile MI*16 x NJ*16).
// 3 LDS buffers, depth-2 counted vmcnt (T3+T4), source-side XOR swizzle (T2),
// XCD chunk swizzle (T1). No split-K: epilogue fused per EPI.
// EPI: 0 = bf16 store; 2 = f32 store + resid; 3 = dt softplus bf16 + x_dbl f32
template <int MI, int NJ, int EPI>
__global__ __launch_bounds__(256) void gemm_t(
    const unsigned short* __restrict__ A, const unsigned short* __restrict__ B,
    int M, int N, int K, int nx,
    float* __restrict__ outf, unsigned short* __restrict__ outb,
    const float* __restrict__ aux, const float* __restrict__ resid) {
  constexpr int BM = MI * 32, BN = NJ * 32;
  constexpr int SA = MI / 2, SB = NJ / 2, S = SA + SB;
  __shared__ __align__(16) unsigned short As[3 * BM * 32];
  __shared__ __align__(16) unsigned short Bs[3 * BN * 32];
  const int tid = threadIdx.x;
  const int lane = tid & 63;
  const int wave = tid >> 6;
  const int wm = wave >> 1, wn = wave & 1;

  // T1: XCD-aware bijective chunk swizzle (nwg % 8 == 0)
  const int nwg = gridDim.x;
  const int wg = blockIdx.x;
  const int swzb = (wg & 7) * (nwg >> 3) + (wg >> 3);
  const int bx = swzb % nx, by = swzb / nx;
  const int bm = by * BM, bn = bx * BN;
  const int nk = K >> 5;

  // staging: LDS dest linear (tid*16B per 64-row chunk); source col-group XOR (T2, rule #21)
  const int srow = tid >> 2, sc4 = tid & 3;
  const int scp = sc4 ^ ((srow >> 1) & 3);
  const unsigned short* Ag = A + (size_t)(bm + srow) * K + scp * 8;
  const unsigned short* Bg = B + (size_t)(bn + srow) * K + scp * 8;
  unsigned short* AsW = &As[srow * 32 + sc4 * 8];
  unsigned short* BsW = &Bs[srow * 32 + sc4 * 8];

  auto STAGE = [&](int buf, int k0) {
#pragma unroll
    for (int q = 0; q < SA; ++q)
      gload_lds16(Ag + (size_t)q * 64 * K + k0, AsW + buf * BM * 32 + q * 64 * 32);
#pragma unroll
    for (int q = 0; q < SB; ++q)
      gload_lds16(Bg + (size_t)q * 64 * K + k0, BsW + buf * BN * 32 + q * 64 * 32);
  };

  f32x4 acc[MI][NJ] = {};

  const int g = lane >> 4;
  const int r16 = lane & 15;
  const int sw = (g ^ ((r16 >> 1) & 3)) * 8;  // read-side of the same XOR

  STAGE(0, 0);
  STAGE(1, 32);
  int cur = 0, stg = 2;

  for (int i = 0; i < nk; ++i) {
    if (i < nk - 1) {
      if constexpr (S == 2) asm volatile("s_waitcnt vmcnt(2)" ::: "memory");
      else if constexpr (S == 3) asm volatile("s_waitcnt vmcnt(3)" ::: "memory");
      else asm volatile("s_waitcnt vmcnt(4)" ::: "memory");
    } else {
      asm volatile("s_waitcnt vmcnt(0)" ::: "memory");
    }
    __builtin_amdgcn_s_barrier();
    asm volatile("" ::: "memory");
    if (i + 2 < nk) {
      STAGE(stg, (i + 2) * 32);
      stg = (stg == 2) ? 0 : stg + 1;
    }

    bf16x8 a[MI], b[NJ];
#pragma unroll
    for (int ii = 0; ii < MI; ++ii)
      a[ii] = *(const bf16x8*)&As[cur * BM * 32 + (wm * MI * 16 + ii * 16 + r16) * 32 + sw];
#pragma unroll
    for (int j = 0; j < NJ; ++j)
      b[j] = *(const bf16x8*)&Bs[cur * BN * 32 + (wn * NJ * 16 + j * 16 + r16) * 32 + sw];
#pragma unroll
    for (int ii = 0; ii < MI; ++ii)
#pragma unroll
      for (int j = 0; j < NJ; ++j)
        acc[ii][j] = __builtin_amdgcn_mfma_f32_16x16x32_bf16(a[ii], b[j], acc[ii][j], 0, 0, 0);

    cur = (cur == 2) ? 0 : cur + 1;
  }

  const int rq = lane >> 4;
#pragma unroll
  for (int i = 0; i < MI; ++i)
#pragma unroll
    for (int j = 0; j < NJ; ++j)
#pragma unroll
      for (int r = 0; r < 4; ++r) {
        int row = bm + wm * MI * 16 + i * 16 + rq * 4 + r;
        int col = bn + wn * NJ * 16 + j * 16 + r16;
        float v = acc[i][j][r];
        if (EPI == 0) {
          outb[(size_t)row * N + col] = f2bf(v);
        } else if (EPI == 2) {
          size_t off = (size_t)row * N + col;
          outf[off] = v + resid[off];
        } else {  // EPI == 3: dt softplus -> bf16; x_dbl extract
          if (col < 2048) {
            float t = v + aux[col];
            float sp = (t > 15.f) ? t : log1pf(__expf(t));
            outb[(size_t)row * 2048 + col] = f2bf(sp);
          } else if (col < 2080) {
            outf[(size_t)row * 32 + (col - 2048)] = v;
          }
        }
      }
}

// ---------------- causal depthwise conv (D_CONV=4) + SiLU; also silu(z) ----------------
__global__ __launch_bounds__(256) void conv_silu8(
    const unsigned short* __restrict__ xz,
    const float* __restrict__ cw, const float* __restrict__ cb,
    unsigned short* __restrict__ x_ssm, unsigned short* __restrict__ sz_out) {
  int idx = blockIdx.x * 256 + threadIdx.x;  // 2048 l * 256 cgroups
  int l = idx >> 8, c0 = (idx & 255) * 8;
  float acc[8];
  float4 b0 = *(const float4*)(cb + c0);
  float4 b1 = *(const float4*)(cb + c0 + 4);
  acc[0] = b0.x; acc[1] = b0.y; acc[2] = b0.z; acc[3] = b0.w;
  acc[4] = b1.x; acc[5] = b1.y; acc[6] = b1.z; acc[7] = b1.w;
  float4 w[8];
#pragma unroll
  for (int j = 0; j < 8; ++j) w[j] = *(const float4*)(cw + (c0 + j) * 4);
#pragma unroll
  for (int k = 0; k < 4; ++k) {
    int lt = l - 3 + k;
    if (lt >= 0) {
      bf16x8 v = *(const bf16x8*)(xz + (size_t)lt * 4096 + c0);
      const float* wk = (const float*)w;
#pragma unroll
      for (int j = 0; j < 8; ++j)
        acc[j] = fmaf(bf2f((unsigned short)v[j]), wk[j * 4 + k], acc[j]);
    }
  }
  bf16x8 zr = *(const bf16x8*)(xz + (size_t)l * 4096 + 2048 + c0);
  bf16x8 ox, oz;
#pragma unroll
  for (int j = 0; j < 8; ++j) {
    float a = acc[j];
    ox[j] = (short)f2bf(a / (1.f + __expf(-a)));
    float zv = bf2f((unsigned short)zr[j]);
    oz[j] = (short)f2bf(zv / (1.f + __expf(-zv)));
  }
  *(bf16x8*)(x_ssm + (size_t)idx * 8) = ox;
  *(bf16x8*)(sz_out + (size_t)idx * 8) = oz;
}

// ---------------- chunked parallel scan, thread-per-channel (16 states in regs) ----------
__global__ __launch_bounds__(256) void scan_passA(
    const unsigned short* __restrict__ dtb, const unsigned short* __restrict__ x_ssm,
    const float* __restrict__ x_dbl, const float* __restrict__ A_log,
    float* __restrict__ Pout, float* __restrict__ Hout) {
  int tid = threadIdx.x;
  int c = blockIdx.x & (NCHUNK - 1), db = blockIdx.x / NCHUNK;
  int d = db * 256 + tid;
  int t0 = c * TCHUNK;
  float Av[16];
  const float4* al4 = (const float4*)(A_log + d * 16);
#pragma unroll
  for (int q = 0; q < 4; ++q) {
    float4 a = al4[q];
    Av[q * 4 + 0] = -__expf(a.x); Av[q * 4 + 1] = -__expf(a.y);
    Av[q * 4 + 2] = -__expf(a.z); Av[q * 4 + 3] = -__expf(a.w);
  }
  float h[16];
#pragma unroll
  for (int s = 0; s < 16; ++s) h[s] = 0.f;
  float sum_dt = 0.f;
#pragma unroll 2
  for (int i = 0; i < TCHUNK; ++i) {
    int t = t0 + i;
    float dtv = bf2f(dtb[(size_t)t * 2048 + d]);
    float xv = bf2f(x_ssm[(size_t)t * 2048 + d]);
    float dtx = dtv * xv;
    sum_dt += dtv;
    const float* B = x_dbl + t * 32;  // wave-uniform -> scalar loads
#pragma unroll
    for (int s = 0; s < 16; ++s) {
      float dA = __expf(dtv * Av[s]);
      h[s] = fmaf(dA, h[s], B[s] * dtx);
    }
  }
  float* Ho = Hout + (size_t)c * 32768 + d * 16;
  float* Po = Pout + (size_t)c * 32768 + d * 16;
#pragma unroll
  for (int s = 0; s < 16; ++s) Ho[s] = h[s];
#pragma unroll
  for (int s = 0; s < 16; ++s) Po[s] = __expf(sum_dt * Av[s]);
}

// Pass B: serial combine; rewrites P buffer in-place with chunk-entry states (Hinit).
__global__ __launch_bounds__(256) void scan_passB(
    float* __restrict__ P, const float* __restrict__ Hloc) {
  int i = blockIdx.x * 256 + threadIdx.x;  // 32768 (d,s)
  float h = 0.f;
#pragma unroll 8
  for (int c = 0; c < NCHUNK; ++c) {
    size_t o = (size_t)c * 32768 + i;
    float p = P[o];
    float hl = Hloc[o];
    P[o] = h;
    h = fmaf(p, h, hl);
  }
}

// Pass C: re-run chunk from entry state; emit gated y (bf16).
__global__ __launch_bounds__(256) void scan_passC(
    const unsigned short* __restrict__ dtb, const unsigned short* __restrict__ x_ssm,
    const float* __restrict__ x_dbl, const float* __restrict__ A_log,
    const float* __restrict__ D_param, const unsigned short* __restrict__ silu_z,
    const float* __restrict__ Hinit, unsigned short* __restrict__ y_out) {
  int tid = threadIdx.x;
  int c = blockIdx.x & (NCHUNK - 1), db = blockIdx.x / NCHUNK;
  int d = db * 256 + tid;
  int t0 = c * TCHUNK;
  float Av[16];
  const float4* al4 = (const float4*)(A_log + d * 16);
#pragma unroll
  for (int q = 0; q < 4; ++q) {
    float4 a = al4[q];
    Av[q * 4 + 0] = -__expf(a.x); Av[q * 4 + 1] = -__expf(a.y);
    Av[q * 4 + 2] = -__expf(a.z); Av[q * 4 + 3] = -__expf(a.w);
  }
  float Dp = D_param[d];
  float h[16];
  const float4* hi4 = (const float4*)(Hinit + (size_t)c * 32768 + d * 16);
#pragma unroll
  for (int q = 0; q < 4; ++q) {
    float4 v = hi4[q];
    h[q * 4 + 0] = v.x; h[q * 4 + 1] = v.y; h[q * 4 + 2] = v.z; h[q * 4 + 3] = v.w;
  }
#pragma unroll 2
  for (int i = 0; i < TCHUNK; ++i) {
    int t = t0 + i;
    float dtv = bf2f(dtb[(size_t)t * 2048 + d]);
    float xv = bf2f(x_ssm[(size_t)t * 2048 + d]);
    float dtx = dtv * xv;
    const float* B = x_dbl + t * 32;       // uniform
    const float* C = x_dbl + t * 32 + 16;  // uniform
    float y = 0.f;
#pragma unroll
    for (int s = 0; s < 16; ++s) {
      float dA = __expf(dtv * Av[s]);
      h[s] = fmaf(dA, h[s], B[s] * dtx);
      y = fmaf(h[s], C[s], y);
    }
    float szv = bf2f(silu_z[(size_t)t * 2048 + d]);
    y_out[(size_t)t * 2048 + d] = f2bf((y + Dp * xv) * szv);
  }
}

extern "C" void kernel_launch(void* const* d_in, const int* in_sizes, int n_in,
                              void* d_out, int out_size, void* d_ws, size_t ws_size,
                              hipStream_t stream) {
  const float* x      = (const float*)d_in[0];
  const float* W_in   = (const float*)d_in[1];
  const float* conv_w = (const float*)d_in[2];
  const float* conv_b = (const float*)d_in[3];
  const float* A_log  = (const float*)d_in[4];
  const float* D_par  = (const float*)d_in[5];
  const float* W_x    = (const float*)d_in[6];
  const float* W_dt   = (const float*)d_in[7];
  const float* b_dt   = (const float*)d_in[8];
  const float* W_out  = (const float*)d_in[9];
  float* out = (float*)d_out;

  // Workspace: all buffers disjoint (peak 90MB of ~256MB) — no aliasing risk.
  char* ws = (char*)d_ws;
  unsigned short* xbf    = (unsigned short*)(ws + 0);                    // 4MB
  unsigned short* Winbf  = (unsigned short*)(ws + ((size_t)4 << 20));    // 8MB
  unsigned short* Wcomb  = (unsigned short*)(ws + ((size_t)12 << 20));   // 8.5MB [2176][2048]
  unsigned short* Woutbf = (unsigned short*)(ws + ((size_t)21 << 20));   // 4MB
  unsigned short* xz     = (unsigned short*)(ws + ((size_t)25 << 20));   // 16MB
  unsigned short* xssm   = (unsigned short*)(ws + ((size_t)41 << 20));   // 8MB
  unsigned short* siluz  = (unsigned short*)(ws + ((size_t)49 << 20));   // 8MB
  unsigned short* dtb    = (unsigned short*)(ws + ((size_t)57 << 20));   // 8MB
  float* xdbl            = (float*)(ws + ((size_t)65 << 20));            // 256KB
  unsigned short* yfin   = (unsigned short*)(ws + ((size_t)66 << 20));   // 8MB
  float* Pbuf            = (float*)(ws + ((size_t)74 << 20));            // 8MB (also Hinit)
  float* Hloc            = (float*)(ws + ((size_t)82 << 20));            // 8MB

  // fused fp32->bf16 converts
  cvt_all<<<12544, 256, 0, stream>>>(
      (const float4*)x, (const float4*)W_in, (const float4*)W_dt, (const float4*)W_x,
      (const float4*)W_out,
      (ushort4*)xbf, (ushort4*)Winbf, (ushort4*)Wcomb,
      (ushort4*)(Wcomb + (size_t)2048 * 2048), (ushort4*)Woutbf,
      (ushort4*)(Wcomb + (size_t)2080 * 2048));

  // GEMM1: xz[2048,4096] = x @ W_in^T — 64x128 tiles, 1024 blocks (4/CU)
  gemm_t<2, 4, 0><<<1024, 256, 0, stream>>>(xbf, Winbf, L_SEQ, 4096, DMODEL, 32,
                                            nullptr, xz, nullptr, nullptr);

  // conv + silu -> x_ssm; silu(z)
  conv_silu8<<<2048, 256, 0, stream>>>(xz, conv_w, conv_b, xssm, siluz);

  // GEMM2: dt bf16 (softplus fused) + x_dbl f32 — 64x128 tiles, 544 blocks
  gemm_t<2, 4, 3><<<544, 256, 0, stream>>>(xssm, Wcomb, L_SEQ, 2176, DINNER, 17,
                                           xdbl, dtb, b_dt, nullptr);

  // chunked parallel scan
  scan_passA<<<NCHUNK * (DINNER / 256), 256, 0, stream>>>(dtb, xssm, xdbl, A_log, Pbuf, Hloc);
  scan_passB<<<(DINNER * 16) / 256, 256, 0, stream>>>(Pbuf, Hloc);
  scan_passC<<<NCHUNK * (DINNER / 256), 256, 0, stream>>>(dtb, xssm, xdbl, A_log, D_par, siluz,
                                                          Pbuf, yfin);

  // GEMM4: out f32 = y @ W_out^T + x — 64x64 tiles, 512 blocks, residual fused
  gemm_t<2, 2, 2><<<512, 256, 0, stream>>>(yfin, Woutbf, L_SEQ, DMODEL, DINNER, 16,
                                           out, nullptr, nullptr, x);
}